// Round 17
// baseline (654.103 us; speedup 1.0000x reference)
//
#include <hip/hip_runtime.h>
#include <hip/hip_bf16.h>
#include <math.h>

#define BB 8
#define NN 1024
#define KK 40
#define EMBD 1024
#define EPSF 1e-5f
#define ROWS 8
#define BBNN (BB * NN)

// 64-bit max with DPP permutation (VALU pipe only; no LDS traffic)
template <int CTRL>
__device__ __forceinline__ unsigned long long dppmax64(unsigned long long cur) {
    unsigned olo = (unsigned)__builtin_amdgcn_update_dpp(0, (int)(unsigned)cur, CTRL, 0xf, 0xf, true);
    unsigned ohi = (unsigned)__builtin_amdgcn_update_dpp(0, (int)(unsigned)(cur >> 32), CTRL, 0xf, 0xf, true);
    unsigned long long o = ((unsigned long long)ohi << 32) | olo;
    return o > cur ? o : cur;
}

// ---------------- fused layer front: knn (blocks 0..BB*128) + yab (rest) ----------------
__global__ __launch_bounds__(256) void layer_kernel(const float* __restrict__ x, int C, int bstride,
                                                    const float* __restrict__ w, int O,
                                                    int* __restrict__ gidx,
                                                    float* __restrict__ ya, float* __restrict__ yc) {
    extern __shared__ float lds[];
    int tid = threadIdx.x;

    if (blockIdx.x < BB * 128) {
        // ================= knn role =================
        float* S = lds;                  // ROWS*NN = 32 KB
        int b = blockIdx.x >> 7;
        int n0 = (blockIdx.x & 127) * ROWS;
        const float* xb = x + (size_t)b * bstride;

        float acc[ROWS][4];
        float xxa[4] = {0.f, 0.f, 0.f, 0.f};
#pragma unroll
        for (int r = 0; r < ROWS; ++r)
#pragma unroll
            for (int j = 0; j < 4; ++j) acc[r][j] = 0.f;

        for (int c = 0; c < C; ++c) {
            float4 xm  = *(const float4*)&xb[c * NN + (tid << 2)];
            float4 ce0 = *(const float4*)&xb[c * NN + n0];        // wave-uniform -> s_load
            float4 ce1 = *(const float4*)&xb[c * NN + n0 + 4];
            xxa[0] = fmaf(xm.x, xm.x, xxa[0]);
            xxa[1] = fmaf(xm.y, xm.y, xxa[1]);
            xxa[2] = fmaf(xm.z, xm.z, xxa[2]);
            xxa[3] = fmaf(xm.w, xm.w, xxa[3]);
            float ce[8] = {ce0.x, ce0.y, ce0.z, ce0.w, ce1.x, ce1.y, ce1.z, ce1.w};
#pragma unroll
            for (int r = 0; r < ROWS; ++r) {
                acc[r][0] = fmaf(ce[r], xm.x, acc[r][0]);
                acc[r][1] = fmaf(ce[r], xm.y, acc[r][1]);
                acc[r][2] = fmaf(ce[r], xm.z, acc[r][2]);
                acc[r][3] = fmaf(ce[r], xm.w, acc[r][3]);
            }
        }
#pragma unroll
        for (int r = 0; r < ROWS; ++r) {
            float4 sv;
            sv.x = 2.f * acc[r][0] - xxa[0];
            sv.y = 2.f * acc[r][1] - xxa[1];
            sv.z = 2.f * acc[r][2] - xxa[2];
            sv.w = 2.f * acc[r][3] - xxa[3];
            *(float4*)&S[r * NN + (tid << 2)] = sv;
        }
        __syncthreads();

        // ---- selection: 2 rows/wave; packed-key bitonic sort + DPP pop-head tournament ----
        int wave = tid >> 6, lane = tid & 63;
        int ra = wave << 1, rb = ra + 1;
        unsigned long long va[16], vb[16];
#pragma unroll
        for (int j = 0; j < 16; ++j) {
            unsigned ua = __float_as_uint(S[ra * NN + lane + 64 * j]);
            unsigned ub = __float_as_uint(S[rb * NN + lane + 64 * j]);
            ua ^= (unsigned)((int)ua >> 31) | 0x80000000u;      // monotone float->uint
            ub ^= (unsigned)((int)ub >> 31) | 0x80000000u;
            unsigned lo = (unsigned)(1023 - (lane + (j << 6))); // tie -> min index wins
            va[j] = ((unsigned long long)ua << 32) | lo;
            vb[j] = ((unsigned long long)ub << 32) | lo;
        }
        // bitonic sort ascending: va[15] = lane max
#pragma unroll
        for (int k = 2; k <= 16; k <<= 1)
#pragma unroll
        for (int s = k >> 1; s > 0; s >>= 1)
#pragma unroll
        for (int i = 0; i < 16; ++i) {
            int l = i ^ s;
            if (l > i) {
                bool up = ((i & k) == 0);
                { unsigned long long A = va[i], B = va[l];
                  bool sw = up ? (A > B) : (A < B);
                  va[i] = sw ? B : A; va[l] = sw ? A : B; }
                { unsigned long long A = vb[i], B = vb[l];
                  bool sw = up ? (A > B) : (A < B);
                  vb[i] = sw ? B : A; vb[l] = sw ? A : B; }
            }
        }
        int* ga = gidx + (size_t)b * NN + n0 + ra;
        int* gb = gidx + (size_t)b * NN + n0 + rb;
        unsigned long long ha = va[15], hb = vb[15];
        for (int it = 0; it < KK; ++it) {
            unsigned long long ma = ha, mb = hb;
            ma = dppmax64<0x111>(ma); mb = dppmax64<0x111>(mb);   // row_shr:1
            ma = dppmax64<0x112>(ma); mb = dppmax64<0x112>(mb);   // row_shr:2
            ma = dppmax64<0x114>(ma); mb = dppmax64<0x114>(mb);   // row_shr:4
            ma = dppmax64<0x118>(ma); mb = dppmax64<0x118>(mb);   // row_shr:8
            ma = dppmax64<0x142>(ma); mb = dppmax64<0x142>(mb);   // row_bcast15
            ma = dppmax64<0x143>(ma); mb = dppmax64<0x143>(mb);   // row_bcast31 -> lane63 = max
            unsigned wla = (unsigned)__builtin_amdgcn_readlane((int)(unsigned)ma, 63);
            unsigned wha = (unsigned)__builtin_amdgcn_readlane((int)(unsigned)(ma >> 32), 63);
            unsigned wlb = (unsigned)__builtin_amdgcn_readlane((int)(unsigned)mb, 63);
            unsigned whb = (unsigned)__builtin_amdgcn_readlane((int)(unsigned)(mb >> 32), 63);
            if (lane == 0) {
                ga[(size_t)it * BBNN] = 1023 - (int)wla;
                gb[(size_t)it * BBNN] = 1023 - (int)wlb;
            }
            unsigned long long wka = ((unsigned long long)wha << 32) | wla;
            unsigned long long wkb = ((unsigned long long)whb << 32) | wlb;
            bool pa = (ha == wka), pb = (hb == wkb);   // unique keys: exactly one lane pops
#pragma unroll
            for (int j = 15; j > 0; --j) {
                va[j] = pa ? va[j - 1] : va[j];
                vb[j] = pb ? vb[j - 1] : vb[j];
            }
            va[0] = pa ? 0ull : va[0];
            vb[0] = pb ? 0ull : vb[0];
            ha = va[15]; hb = vb[15];
        }
    } else {
        // ================= yab role =================
        int bid = blockIdx.x - BB * 128;
        float* wls = lds;                // [8*C] wa, then [8*C] wc
        int opb = O >> 3;
        int b  = bid / opb;
        int o0 = (bid % opb) << 3;
        const float* xb = x + (size_t)b * bstride;

        for (int t = tid; t < 8 * C; t += 256) {
            int r = t / C, c = t - r * C;
            float wa = w[(size_t)(o0 + r) * 2 * C + c];
            float wb = w[(size_t)(o0 + r) * 2 * C + C + c];
            wls[t] = wa;
            wls[8 * C + t] = wb - wa;
        }
        __syncthreads();

        float a[8][4], cv[8][4];
#pragma unroll
        for (int r = 0; r < 8; ++r)
#pragma unroll
            for (int j = 0; j < 4; ++j) { a[r][j] = 0.f; cv[r][j] = 0.f; }
        for (int c = 0; c < C; ++c) {
            float4 xm = *(const float4*)&xb[c * NN + (tid << 2)];
#pragma unroll
            for (int r = 0; r < 8; ++r) {
                float wa = wls[r * C + c];
                float wc = wls[8 * C + r * C + c];
                a[r][0]  = fmaf(wa, xm.x, a[r][0]);  cv[r][0] = fmaf(wc, xm.x, cv[r][0]);
                a[r][1]  = fmaf(wa, xm.y, a[r][1]);  cv[r][1] = fmaf(wc, xm.y, cv[r][1]);
                a[r][2]  = fmaf(wa, xm.z, a[r][2]);  cv[r][2] = fmaf(wc, xm.z, cv[r][2]);
                a[r][3]  = fmaf(wa, xm.w, a[r][3]);  cv[r][3] = fmaf(wc, xm.w, cv[r][3]);
            }
        }
#pragma unroll
        for (int r = 0; r < 8; ++r) {
            size_t off = ((size_t)b * O + o0 + r) * NN + (tid << 2);
            *(float4*)&ya[off] = *(float4*)&a[r][0];
            *(float4*)&yc[off] = *(float4*)&cv[r][0];
        }
    }
}

// ---------------- gmax2: 2 o-rows per block (8 KB LDS), high occupancy ----------------
__global__ __launch_bounds__(256) void gmax2_kernel(const float* __restrict__ ya, const float* __restrict__ yc,
                                                    const int* __restrict__ gidx, const float* __restrict__ bnp,
                                                    int O, float* __restrict__ outp, int out_bstride) {
    __shared__ float yrow[2 * NN];       // 8 KB
    int tid = threadIdx.x;
    int nt   = blockIdx.x & 3;
    int rest = blockIdx.x >> 2;
    int opb = O >> 1;
    int oc = rest % opb;
    int b  = rest / opb;
    int o0 = oc << 1;
    int n  = (nt << 8) + tid;

    // rows o0,o0+1 are contiguous in ya: copy 2048 floats = 512 float4
    const float4* src = (const float4*)(ya + ((size_t)b * O + o0) * NN);
#pragma unroll
    for (int i = 0; i < 2; ++i)
        ((float4*)yrow)[tid + (i << 8)] = src[tid + (i << 8)];
    __syncthreads();

    int idx[KK];
    const int* gi = gidx + (size_t)b * NN + n;
#pragma unroll
    for (int k = 0; k < KK; ++k) idx[k] = gi[(size_t)k * BBNN];

    float m0 = -INFINITY, m1 = -INFINITY;
#pragma unroll 8
    for (int k = 0; k < KK; ++k) {
        int j = idx[k];
        m0 = fmaxf(m0, yrow[j]);
        m1 = fmaxf(m1, yrow[NN + j]);
    }
    m0 += yc[((size_t)b * O + o0 + 0) * NN + n];
    m1 += yc[((size_t)b * O + o0 + 1) * NN + n];
    {
        int o = o0;
        float sc = bnp[o] * rsqrtf(bnp[3 * O + o] + EPSF);
        float t0 = (m0 - bnp[2 * O + o]) * sc + bnp[O + o];
        outp[(size_t)b * out_bstride + (size_t)o * NN + n] = t0 >= 0.f ? t0 : 0.2f * t0;
    }
    {
        int o = o0 + 1;
        float sc = bnp[o] * rsqrtf(bnp[3 * O + o] + EPSF);
        float t0 = (m1 - bnp[2 * O + o]) * sc + bnp[O + o];
        outp[(size_t)b * out_bstride + (size_t)o * NN + n] = t0 >= 0.f ? t0 : 0.2f * t0;
    }
}

// ---------------- emb v6: XCD-local, SGPR w5 (s_load, no LDS), 8o x 4n per thread ----------------
__global__ __launch_bounds__(256) void emb_kernel(const float* __restrict__ xc, const float* __restrict__ w5,
                                                  const float* __restrict__ bnp, float* __restrict__ g) {
    __shared__ float rmax[8][4], rsum[8][4];
    int tid = threadIdx.x;
    int b  = blockIdx.x & 7;             // XCD-local batches
    int o0 = (blockIdx.x >> 3) << 3;     // 128 o-blocks of 8
    const float* xcb = xc + (size_t)b * 512 * NN;
    const float* wr  = w5 + (size_t)o0 * 512;

    int n4 = tid << 2;
    float acc[8][4];
#pragma unroll
    for (int r = 0; r < 8; ++r)
#pragma unroll
        for (int j = 0; j < 4; ++j) acc[r][j] = 0.f;

#pragma unroll 2
    for (int c4 = 0; c4 < 128; ++c4) {
        int c = c4 << 2;
        float4 xm0 = *(const float4*)&xcb[(c + 0) * NN + n4];
        float4 xm1 = *(const float4*)&xcb[(c + 1) * NN + n4];
        float4 xm2 = *(const float4*)&xcb[(c + 2) * NN + n4];
        float4 xm3 = *(const float4*)&xcb[(c + 3) * NN + n4];
#pragma unroll
        for (int r = 0; r < 8; ++r) {
            float4 wv = *(const float4*)&wr[r * 512 + c];   // uniform addr -> s_load_dwordx4
            acc[r][0] = fmaf(wv.x, xm0.x, acc[r][0]);
            acc[r][1] = fmaf(wv.x, xm0.y, acc[r][1]);
            acc[r][2] = fmaf(wv.x, xm0.z, acc[r][2]);
            acc[r][3] = fmaf(wv.x, xm0.w, acc[r][3]);
            acc[r][0] = fmaf(wv.y, xm1.x, acc[r][0]);
            acc[r][1] = fmaf(wv.y, xm1.y, acc[r][1]);
            acc[r][2] = fmaf(wv.y, xm1.z, acc[r][2]);
            acc[r][3] = fmaf(wv.y, xm1.w, acc[r][3]);
            acc[r][0] = fmaf(wv.z, xm2.x, acc[r][0]);
            acc[r][1] = fmaf(wv.z, xm2.y, acc[r][1]);
            acc[r][2] = fmaf(wv.z, xm2.z, acc[r][2]);
            acc[r][3] = fmaf(wv.z, xm2.w, acc[r][3]);
            acc[r][0] = fmaf(wv.w, xm3.x, acc[r][0]);
            acc[r][1] = fmaf(wv.w, xm3.y, acc[r][1]);
            acc[r][2] = fmaf(wv.w, xm3.z, acc[r][2]);
            acc[r][3] = fmaf(wv.w, xm3.w, acc[r][3]);
        }
    }

    int lane = tid & 63, wave = tid >> 6;
#pragma unroll
    for (int r = 0; r < 8; ++r) {
        int o = o0 + r;
        float sc = bnp[o] * rsqrtf(bnp[3 * EMBD + o] + EPSF);
        float mu = bnp[2 * EMBD + o], be = bnp[EMBD + o];
        float vmax = -INFINITY, vsum = 0.f;
#pragma unroll
        for (int j = 0; j < 4; ++j) {
            float t0 = (acc[r][j] - mu) * sc + be;
            t0 = t0 >= 0.f ? t0 : 0.2f * t0;
            vmax = fmaxf(vmax, t0);
            vsum += t0;
        }
#pragma unroll
        for (int off = 32; off >= 1; off >>= 1) {
            vmax = fmaxf(vmax, __shfl_xor(vmax, off));
            vsum += __shfl_xor(vsum, off);
        }
        if (lane == 0) { rmax[r][wave] = vmax; rsum[r][wave] = vsum; }
    }
    __syncthreads();
    if (tid < 8) {
        float vm = fmaxf(fmaxf(rmax[tid][0], rmax[tid][1]), fmaxf(rmax[tid][2], rmax[tid][3]));
        g[(size_t)b * 2 * EMBD + o0 + tid] = vm;
    } else if (tid < 16) {
        int r = tid - 8;
        float vs = rsum[r][0] + rsum[r][1] + rsum[r][2] + rsum[r][3];
        g[(size_t)b * 2 * EMBD + EMBD + o0 + r] = vs * (1.0f / 1024.0f);
    }
}

// ---------------- fused head: one block per b; g->h1->h2->logits->logsm all in LDS ----------------
__global__ __launch_bounds__(512) void head_fused_kernel(const float* __restrict__ g,
                                                         const float* __restrict__ l1, const float* __restrict__ bn6,
                                                         const float* __restrict__ l2w, const float* __restrict__ l2b,
                                                         const float* __restrict__ bn7,
                                                         const float* __restrict__ l3w, const float* __restrict__ l3b,
                                                         float* __restrict__ outp) {
    __shared__ float gs[2 * EMBD];       // 8 KB
    __shared__ float h1s[512];
    __shared__ float h2s[256];
    __shared__ float lg[64];
    int tid = threadIdx.x;
    int b = blockIdx.x;

    for (int t = tid; t < 2 * EMBD; t += 512) gs[t] = g[(size_t)b * 2 * EMBD + t];
    __syncthreads();

    {   // h1: 512 outputs, 1 per thread; dot over 2048
        int o = tid;
        const float4* lr  = (const float4*)(l1 + (size_t)o * 2 * EMBD);
        const float4* gs4 = (const float4*)gs;
        float s = 0.f;
        for (int c = 0; c < 512; ++c) {
            float4 a = lr[c], v = gs4[c];
            s += a.x * v.x + a.y * v.y + a.z * v.z + a.w * v.w;
        }
        float sc = bn6[o] * rsqrtf(bn6[3 * 512 + o] + EPSF);
        float t0 = (s - bn6[2 * 512 + o]) * sc + bn6[512 + o];
        h1s[o] = t0 >= 0.f ? t0 : 0.2f * t0;
    }
    __syncthreads();

    if (tid < 256) {    // h2: 256 outputs; dot over 512
        int o = tid;
        const float4* lr  = (const float4*)(l2w + (size_t)o * 512);
        const float4* h14 = (const float4*)h1s;
        float s = l2b[o];
        for (int c = 0; c < 128; ++c) {
            float4 a = lr[c], v = h14[c];
            s += a.x * v.x + a.y * v.y + a.z * v.z + a.w * v.w;
        }
        float sc = bn7[o] * rsqrtf(bn7[3 * 256 + o] + EPSF);
        float t0 = (s - bn7[2 * 256 + o]) * sc + bn7[256 + o];
        h2s[o] = t0 >= 0.f ? t0 : 0.2f * t0;
    }
    __syncthreads();

    if (tid < 64) {     // h3: 40 logits on one wave
        float s = -INFINITY;
        if (tid < 40) {
            s = l3b[tid];
            const float4* lr  = (const float4*)(l3w + (size_t)tid * 256);
            const float4* h24 = (const float4*)h2s;
            for (int c = 0; c < 64; ++c) {
                float4 a = lr[c], v = h24[c];
                s += a.x * v.x + a.y * v.y + a.z * v.z + a.w * v.w;
            }
            outp[b * 40 + tid] = s;
        }
        float mx = s;
#pragma unroll
        for (int off = 32; off >= 1; off >>= 1) mx = fmaxf(mx, __shfl_xor(mx, off));
        float e = (tid < 40) ? expf(s - mx) : 0.f;
#pragma unroll
        for (int off = 32; off >= 1; off >>= 1) e += __shfl_xor(e, off);
        if (tid < 40) outp[BB * 40 + b * 40 + tid] = s - mx - logf(e);
    }
    (void)lg;
}

extern "C" void kernel_launch(void* const* d_in, const int* in_sizes, int n_in,
                              void* d_out, int out_size, void* d_ws, size_t ws_size,
                              hipStream_t stream) {
    const float* x   = (const float*)d_in[0];
    const float* w1  = (const float*)d_in[1];
    const float* w2  = (const float*)d_in[2];
    const float* w3  = (const float*)d_in[3];
    const float* w4  = (const float*)d_in[4];
    const float* w5  = (const float*)d_in[5];
    const float* l1  = (const float*)d_in[6];
    const float* l2w = (const float*)d_in[7];
    const float* l2b = (const float*)d_in[8];
    const float* l3w = (const float*)d_in[9];
    const float* l3b = (const float*)d_in[10];
    const float* bn1 = (const float*)d_in[11];
    const float* bn2 = (const float*)d_in[12];
    const float* bn3 = (const float*)d_in[13];
    const float* bn4 = (const float*)d_in[14];
    const float* bn5 = (const float*)d_in[15];
    const float* bn6 = (const float*)d_in[16];
    const float* bn7 = (const float*)d_in[17];
    float* outp = (float*)d_out;   // reference outputs are float32

    // workspace carve (floats): xc | ya | yc | gidx | g
    float* xc     = (float*)d_ws;
    float* ya     = xc  + (size_t)BB * 512 * NN;
    float* ycb    = ya  + (size_t)BB * 256 * NN;
    int*  gidx    = (int*)(ycb + (size_t)BB * 256 * NN);
    float* g      = (float*)(gidx + (size_t)BB * NN * KK);

    struct Layer { const float* xin; int C; int bstride; const float* w; const float* bn; int O; float* out; };
    Layer L[4] = {
        { x,            3,   3 * NN,   w1, bn1, 64,  xc            },
        { xc,           64,  512 * NN, w2, bn2, 64,  xc + 64 * NN  },
        { xc + 64 * NN, 64,  512 * NN, w3, bn3, 128, xc + 128 * NN },
        { xc + 128 * NN,128, 512 * NN, w4, bn4, 256, xc + 256 * NN },
    };

    size_t lsz = (size_t)(ROWS * NN) * sizeof(float);   // 32 KB
    for (int i = 0; i < 4; ++i) {
        layer_kernel<<<dim3(BB * 128 + BB * (L[i].O / 8)), dim3(256), lsz, stream>>>(
            L[i].xin, L[i].C, L[i].bstride, L[i].w, L[i].O, gidx, ya, ycb);
        gmax2_kernel<<<dim3(BB * (L[i].O / 2) * 4), dim3(256), 0, stream>>>(ya, ycb, gidx, L[i].bn, L[i].O, L[i].out, 512 * NN);
    }
    emb_kernel<<<dim3(BB * 128), dim3(256), 0, stream>>>(xc, w5, bn5, g);
    head_fused_kernel<<<dim3(BB), dim3(512), 0, stream>>>(g, l1, bn6, l2w, l2b, bn7, l3w, l3b, outp);
}

// Round 18
// 537.229 us; speedup vs baseline: 1.2176x; 1.2176x over previous
//
#include <hip/hip_runtime.h>
#include <hip/hip_bf16.h>
#include <math.h>

#define BB 8
#define NN 1024
#define KK 40
#define EMBD 1024
#define EPSF 1e-5f
#define ROWS 8
#define BBNN (BB * NN)

// 64-bit max with DPP permutation (VALU pipe only; no LDS traffic)
template <int CTRL>
__device__ __forceinline__ unsigned long long dppmax64(unsigned long long cur) {
    unsigned olo = (unsigned)__builtin_amdgcn_update_dpp(0, (int)(unsigned)cur, CTRL, 0xf, 0xf, true);
    unsigned ohi = (unsigned)__builtin_amdgcn_update_dpp(0, (int)(unsigned)(cur >> 32), CTRL, 0xf, 0xf, true);
    unsigned long long o = ((unsigned long long)ohi << 32) | olo;
    return o > cur ? o : cur;
}

// ---------------- fused layer front: knn (blocks 0..BB*128) + yab (rest) ----------------
__global__ __launch_bounds__(256) void layer_kernel(const float* __restrict__ x, int C, int bstride,
                                                    const float* __restrict__ w, int O,
                                                    int* __restrict__ gidx,
                                                    float* __restrict__ ya, float* __restrict__ yc) {
    extern __shared__ float lds[];
    int tid = threadIdx.x;

    if (blockIdx.x < BB * 128) {
        // ================= knn role =================
        float* S = lds;                  // ROWS*NN = 32 KB
        int b = blockIdx.x >> 7;
        int n0 = (blockIdx.x & 127) * ROWS;
        const float* xb = x + (size_t)b * bstride;

        float acc[ROWS][4];
        float xxa[4] = {0.f, 0.f, 0.f, 0.f};
#pragma unroll
        for (int r = 0; r < ROWS; ++r)
#pragma unroll
            for (int j = 0; j < 4; ++j) acc[r][j] = 0.f;

        for (int c = 0; c < C; ++c) {
            float4 xm  = *(const float4*)&xb[c * NN + (tid << 2)];
            float4 ce0 = *(const float4*)&xb[c * NN + n0];        // wave-uniform -> s_load
            float4 ce1 = *(const float4*)&xb[c * NN + n0 + 4];
            xxa[0] = fmaf(xm.x, xm.x, xxa[0]);
            xxa[1] = fmaf(xm.y, xm.y, xxa[1]);
            xxa[2] = fmaf(xm.z, xm.z, xxa[2]);
            xxa[3] = fmaf(xm.w, xm.w, xxa[3]);
            float ce[8] = {ce0.x, ce0.y, ce0.z, ce0.w, ce1.x, ce1.y, ce1.z, ce1.w};
#pragma unroll
            for (int r = 0; r < ROWS; ++r) {
                acc[r][0] = fmaf(ce[r], xm.x, acc[r][0]);
                acc[r][1] = fmaf(ce[r], xm.y, acc[r][1]);
                acc[r][2] = fmaf(ce[r], xm.z, acc[r][2]);
                acc[r][3] = fmaf(ce[r], xm.w, acc[r][3]);
            }
        }
#pragma unroll
        for (int r = 0; r < ROWS; ++r) {
            float4 sv;
            sv.x = 2.f * acc[r][0] - xxa[0];
            sv.y = 2.f * acc[r][1] - xxa[1];
            sv.z = 2.f * acc[r][2] - xxa[2];
            sv.w = 2.f * acc[r][3] - xxa[3];
            *(float4*)&S[r * NN + (tid << 2)] = sv;
        }
        __syncthreads();

        // ---- selection: 2 rows/wave; packed-key bitonic sort + DPP pop-head tournament ----
        int wave = tid >> 6, lane = tid & 63;
        int ra = wave << 1, rb = ra + 1;
        unsigned long long va[16], vb[16];
#pragma unroll
        for (int j = 0; j < 16; ++j) {
            unsigned ua = __float_as_uint(S[ra * NN + lane + 64 * j]);
            unsigned ub = __float_as_uint(S[rb * NN + lane + 64 * j]);
            ua ^= (unsigned)((int)ua >> 31) | 0x80000000u;      // monotone float->uint
            ub ^= (unsigned)((int)ub >> 31) | 0x80000000u;
            unsigned lo = (unsigned)(1023 - (lane + (j << 6))); // tie -> min index wins
            va[j] = ((unsigned long long)ua << 32) | lo;
            vb[j] = ((unsigned long long)ub << 32) | lo;
        }
        // bitonic sort ascending: va[15] = lane max
#pragma unroll
        for (int k = 2; k <= 16; k <<= 1)
#pragma unroll
        for (int s = k >> 1; s > 0; s >>= 1)
#pragma unroll
        for (int i = 0; i < 16; ++i) {
            int l = i ^ s;
            if (l > i) {
                bool up = ((i & k) == 0);
                { unsigned long long A = va[i], B = va[l];
                  bool sw = up ? (A > B) : (A < B);
                  va[i] = sw ? B : A; va[l] = sw ? A : B; }
                { unsigned long long A = vb[i], B = vb[l];
                  bool sw = up ? (A > B) : (A < B);
                  vb[i] = sw ? B : A; vb[l] = sw ? A : B; }
            }
        }
        int* ga = gidx + (size_t)b * NN + n0 + ra;
        int* gb = gidx + (size_t)b * NN + n0 + rb;
        unsigned long long ha = va[15], hb = vb[15];
        for (int it = 0; it < KK; ++it) {
            unsigned long long ma = ha, mb = hb;
            ma = dppmax64<0x111>(ma); mb = dppmax64<0x111>(mb);   // row_shr:1
            ma = dppmax64<0x112>(ma); mb = dppmax64<0x112>(mb);   // row_shr:2
            ma = dppmax64<0x114>(ma); mb = dppmax64<0x114>(mb);   // row_shr:4
            ma = dppmax64<0x118>(ma); mb = dppmax64<0x118>(mb);   // row_shr:8
            ma = dppmax64<0x142>(ma); mb = dppmax64<0x142>(mb);   // row_bcast15
            ma = dppmax64<0x143>(ma); mb = dppmax64<0x143>(mb);   // row_bcast31 -> lane63 = max
            unsigned wla = (unsigned)__builtin_amdgcn_readlane((int)(unsigned)ma, 63);
            unsigned wha = (unsigned)__builtin_amdgcn_readlane((int)(unsigned)(ma >> 32), 63);
            unsigned wlb = (unsigned)__builtin_amdgcn_readlane((int)(unsigned)mb, 63);
            unsigned whb = (unsigned)__builtin_amdgcn_readlane((int)(unsigned)(mb >> 32), 63);
            if (lane == 0) {
                ga[(size_t)it * BBNN] = 1023 - (int)wla;
                gb[(size_t)it * BBNN] = 1023 - (int)wlb;
            }
            unsigned long long wka = ((unsigned long long)wha << 32) | wla;
            unsigned long long wkb = ((unsigned long long)whb << 32) | wlb;
            bool pa = (ha == wka), pb = (hb == wkb);   // unique keys: exactly one lane pops
#pragma unroll
            for (int j = 15; j > 0; --j) {
                va[j] = pa ? va[j - 1] : va[j];
                vb[j] = pb ? vb[j - 1] : vb[j];
            }
            va[0] = pa ? 0ull : va[0];
            vb[0] = pb ? 0ull : vb[0];
            ha = va[15]; hb = vb[15];
        }
    } else {
        // ================= yab role =================
        int bid = blockIdx.x - BB * 128;
        float* wls = lds;                // [8*C] wa, then [8*C] wc
        int opb = O >> 3;
        int b  = bid / opb;
        int o0 = (bid % opb) << 3;
        const float* xb = x + (size_t)b * bstride;

        for (int t = tid; t < 8 * C; t += 256) {
            int r = t / C, c = t - r * C;
            float wa = w[(size_t)(o0 + r) * 2 * C + c];
            float wb = w[(size_t)(o0 + r) * 2 * C + C + c];
            wls[t] = wa;
            wls[8 * C + t] = wb - wa;
        }
        __syncthreads();

        float a[8][4], cv[8][4];
#pragma unroll
        for (int r = 0; r < 8; ++r)
#pragma unroll
            for (int j = 0; j < 4; ++j) { a[r][j] = 0.f; cv[r][j] = 0.f; }
        for (int c = 0; c < C; ++c) {
            float4 xm = *(const float4*)&xb[c * NN + (tid << 2)];
#pragma unroll
            for (int r = 0; r < 8; ++r) {
                float wa = wls[r * C + c];
                float wc = wls[8 * C + r * C + c];
                a[r][0]  = fmaf(wa, xm.x, a[r][0]);  cv[r][0] = fmaf(wc, xm.x, cv[r][0]);
                a[r][1]  = fmaf(wa, xm.y, a[r][1]);  cv[r][1] = fmaf(wc, xm.y, cv[r][1]);
                a[r][2]  = fmaf(wa, xm.z, a[r][2]);  cv[r][2] = fmaf(wc, xm.z, cv[r][2]);
                a[r][3]  = fmaf(wa, xm.w, a[r][3]);  cv[r][3] = fmaf(wc, xm.w, cv[r][3]);
            }
        }
#pragma unroll
        for (int r = 0; r < 8; ++r) {
            size_t off = ((size_t)b * O + o0 + r) * NN + (tid << 2);
            *(float4*)&ya[off] = *(float4*)&a[r][0];
            *(float4*)&yc[off] = *(float4*)&cv[r][0];
        }
    }
}

// ---------------- gmax2: 2 o-rows per block (8 KB LDS), high occupancy ----------------
__global__ __launch_bounds__(256) void gmax2_kernel(const float* __restrict__ ya, const float* __restrict__ yc,
                                                    const int* __restrict__ gidx, const float* __restrict__ bnp,
                                                    int O, float* __restrict__ outp, int out_bstride) {
    __shared__ float yrow[2 * NN];       // 8 KB
    int tid = threadIdx.x;
    int nt   = blockIdx.x & 3;
    int rest = blockIdx.x >> 2;
    int opb = O >> 1;
    int oc = rest % opb;
    int b  = rest / opb;
    int o0 = oc << 1;
    int n  = (nt << 8) + tid;

    const float4* src = (const float4*)(ya + ((size_t)b * O + o0) * NN);
#pragma unroll
    for (int i = 0; i < 2; ++i)
        ((float4*)yrow)[tid + (i << 8)] = src[tid + (i << 8)];
    __syncthreads();

    int idx[KK];
    const int* gi = gidx + (size_t)b * NN + n;
#pragma unroll
    for (int k = 0; k < KK; ++k) idx[k] = gi[(size_t)k * BBNN];

    float m0 = -INFINITY, m1 = -INFINITY;
#pragma unroll 8
    for (int k = 0; k < KK; ++k) {
        int j = idx[k];
        m0 = fmaxf(m0, yrow[j]);
        m1 = fmaxf(m1, yrow[NN + j]);
    }
    m0 += yc[((size_t)b * O + o0 + 0) * NN + n];
    m1 += yc[((size_t)b * O + o0 + 1) * NN + n];
    {
        int o = o0;
        float sc = bnp[o] * rsqrtf(bnp[3 * O + o] + EPSF);
        float t0 = (m0 - bnp[2 * O + o]) * sc + bnp[O + o];
        outp[(size_t)b * out_bstride + (size_t)o * NN + n] = t0 >= 0.f ? t0 : 0.2f * t0;
    }
    {
        int o = o0 + 1;
        float sc = bnp[o] * rsqrtf(bnp[3 * O + o] + EPSF);
        float t0 = (m1 - bnp[2 * O + o]) * sc + bnp[O + o];
        outp[(size_t)b * out_bstride + (size_t)o * NN + n] = t0 >= 0.f ? t0 : 0.2f * t0;
    }
}

// ---------------- emb v6: XCD-local, SGPR w5 (s_load, no LDS), 8o x 4n per thread ----------------
__global__ __launch_bounds__(256) void emb_kernel(const float* __restrict__ xc, const float* __restrict__ w5,
                                                  const float* __restrict__ bnp, float* __restrict__ g) {
    __shared__ float rmax[8][4], rsum[8][4];
    int tid = threadIdx.x;
    int b  = blockIdx.x & 7;             // XCD-local batches
    int o0 = (blockIdx.x >> 3) << 3;     // 128 o-blocks of 8
    const float* xcb = xc + (size_t)b * 512 * NN;
    const float* wr  = w5 + (size_t)o0 * 512;

    int n4 = tid << 2;
    float acc[8][4];
#pragma unroll
    for (int r = 0; r < 8; ++r)
#pragma unroll
        for (int j = 0; j < 4; ++j) acc[r][j] = 0.f;

#pragma unroll 2
    for (int c4 = 0; c4 < 128; ++c4) {
        int c = c4 << 2;
        float4 xm0 = *(const float4*)&xcb[(c + 0) * NN + n4];
        float4 xm1 = *(const float4*)&xcb[(c + 1) * NN + n4];
        float4 xm2 = *(const float4*)&xcb[(c + 2) * NN + n4];
        float4 xm3 = *(const float4*)&xcb[(c + 3) * NN + n4];
#pragma unroll
        for (int r = 0; r < 8; ++r) {
            float4 wv = *(const float4*)&wr[r * 512 + c];   // uniform addr -> s_load_dwordx4
            acc[r][0] = fmaf(wv.x, xm0.x, acc[r][0]);
            acc[r][1] = fmaf(wv.x, xm0.y, acc[r][1]);
            acc[r][2] = fmaf(wv.x, xm0.z, acc[r][2]);
            acc[r][3] = fmaf(wv.x, xm0.w, acc[r][3]);
            acc[r][0] = fmaf(wv.y, xm1.x, acc[r][0]);
            acc[r][1] = fmaf(wv.y, xm1.y, acc[r][1]);
            acc[r][2] = fmaf(wv.y, xm1.z, acc[r][2]);
            acc[r][3] = fmaf(wv.y, xm1.w, acc[r][3]);
            acc[r][0] = fmaf(wv.z, xm2.x, acc[r][0]);
            acc[r][1] = fmaf(wv.z, xm2.y, acc[r][1]);
            acc[r][2] = fmaf(wv.z, xm2.z, acc[r][2]);
            acc[r][3] = fmaf(wv.z, xm2.w, acc[r][3]);
            acc[r][0] = fmaf(wv.w, xm3.x, acc[r][0]);
            acc[r][1] = fmaf(wv.w, xm3.y, acc[r][1]);
            acc[r][2] = fmaf(wv.w, xm3.z, acc[r][2]);
            acc[r][3] = fmaf(wv.w, xm3.w, acc[r][3]);
        }
    }

    int lane = tid & 63, wave = tid >> 6;
#pragma unroll
    for (int r = 0; r < 8; ++r) {
        int o = o0 + r;
        float sc = bnp[o] * rsqrtf(bnp[3 * EMBD + o] + EPSF);
        float mu = bnp[2 * EMBD + o], be = bnp[EMBD + o];
        float vmax = -INFINITY, vsum = 0.f;
#pragma unroll
        for (int j = 0; j < 4; ++j) {
            float t0 = (acc[r][j] - mu) * sc + be;
            t0 = t0 >= 0.f ? t0 : 0.2f * t0;
            vmax = fmaxf(vmax, t0);
            vsum += t0;
        }
#pragma unroll
        for (int off = 32; off >= 1; off >>= 1) {
            vmax = fmaxf(vmax, __shfl_xor(vmax, off));
            vsum += __shfl_xor(vsum, off);
        }
        if (lane == 0) { rmax[r][wave] = vmax; rsum[r][wave] = vsum; }
    }
    __syncthreads();
    if (tid < 8) {
        float vm = fmaxf(fmaxf(rmax[tid][0], rmax[tid][1]), fmaxf(rmax[tid][2], rmax[tid][3]));
        g[(size_t)b * 2 * EMBD + o0 + tid] = vm;
    } else if (tid < 16) {
        int r = tid - 8;
        float vs = rsum[r][0] + rsum[r][1] + rsum[r][2] + rsum[r][3];
        g[(size_t)b * 2 * EMBD + EMBD + o0 + r] = vs * (1.0f / 1024.0f);
    }
}

// ---------------- naive head1: one block per (b,o) ----------------
__global__ __launch_bounds__(256) void head1_naive_kernel(const float* __restrict__ g, const float* __restrict__ l1,
                                                          const float* __restrict__ bnp, float* __restrict__ h1) {
    __shared__ float red[256];
    int tid = threadIdx.x;
    int b = blockIdx.x >> 9, o = blockIdx.x & 511;
    const float* gr = g + (size_t)b * 2 * EMBD;
    const float* lr = l1 + (size_t)o * 2 * EMBD;
    float s = 0.f;
    for (int c = tid; c < 2048; c += 256) s = fmaf(gr[c], lr[c], s);
    red[tid] = s;
    __syncthreads();
    for (int st = 128; st >= 1; st >>= 1) {
        if (tid < st) red[tid] += red[tid + st];
        __syncthreads();
    }
    if (tid == 0) {
        float sc = bnp[o] * rsqrtf(bnp[3 * 512 + o] + EPSF);
        float t0 = (red[0] - bnp[2 * 512 + o]) * sc + bnp[512 + o];
        h1[b * 512 + o] = t0 >= 0.f ? t0 : 0.2f * t0;
    }
}

// ---------------- naive head2: one block per (b,o) ----------------
__global__ __launch_bounds__(256) void head2_naive_kernel(const float* __restrict__ h1, const float* __restrict__ l2w,
                                                          const float* __restrict__ l2b, const float* __restrict__ bnp,
                                                          float* __restrict__ h2) {
    __shared__ float red[256];
    int tid = threadIdx.x;
    int b = blockIdx.x >> 8, o = blockIdx.x & 255;
    const float* hr = h1 + (size_t)b * 512;
    const float* lr = l2w + (size_t)o * 512;
    float s = fmaf(hr[tid], lr[tid], hr[tid + 256] * lr[tid + 256]);
    red[tid] = s;
    __syncthreads();
    for (int st = 128; st >= 1; st >>= 1) {
        if (tid < st) red[tid] += red[tid + st];
        __syncthreads();
    }
    if (tid == 0) {
        float v = red[0] + l2b[o];
        float sc = bnp[o] * rsqrtf(bnp[3 * 256 + o] + EPSF);
        float t0 = (v - bnp[2 * 256 + o]) * sc + bnp[256 + o];
        h2[b * 256 + o] = t0 >= 0.f ? t0 : 0.2f * t0;
    }
}

// ---------------- naive head3: one block per (b,i) -> logits scratch ----------------
__global__ __launch_bounds__(256) void head3_naive_kernel(const float* __restrict__ h2, const float* __restrict__ l3w,
                                                          const float* __restrict__ l3b, float* __restrict__ logits) {
    __shared__ float red[256];
    int tid = threadIdx.x;
    int b = blockIdx.x / 40, i = blockIdx.x % 40;
    red[tid] = h2[(size_t)b * 256 + tid] * l3w[(size_t)i * 256 + tid];
    __syncthreads();
    for (int st = 128; st >= 1; st >>= 1) {
        if (tid < st) red[tid] += red[tid + st];
        __syncthreads();
    }
    if (tid == 0) logits[b * 40 + i] = red[0] + l3b[i];
}

// ---------------- final: out[0..319]=logits (f32), out[320..639]=log_softmax (f32) ----------------
__global__ void final_kernel(const float* __restrict__ logits, float* __restrict__ outp) {
    int b = blockIdx.x;
    if (threadIdx.x != 0) return;
    const float* lr = logits + b * 40;
    float mx = lr[0];
    for (int i = 1; i < 40; ++i) mx = fmaxf(mx, lr[i]);
    float se = 0.f;
    for (int i = 0; i < 40; ++i) se += expf(lr[i] - mx);
    float lse = logf(se);
    for (int i = 0; i < 40; ++i) {
        outp[b * 40 + i]            = lr[i];
        outp[BB * 40 + b * 40 + i]  = lr[i] - mx - lse;
    }
}

extern "C" void kernel_launch(void* const* d_in, const int* in_sizes, int n_in,
                              void* d_out, int out_size, void* d_ws, size_t ws_size,
                              hipStream_t stream) {
    const float* x   = (const float*)d_in[0];
    const float* w1  = (const float*)d_in[1];
    const float* w2  = (const float*)d_in[2];
    const float* w3  = (const float*)d_in[3];
    const float* w4  = (const float*)d_in[4];
    const float* w5  = (const float*)d_in[5];
    const float* l1  = (const float*)d_in[6];
    const float* l2w = (const float*)d_in[7];
    const float* l2b = (const float*)d_in[8];
    const float* l3w = (const float*)d_in[9];
    const float* l3b = (const float*)d_in[10];
    const float* bn1 = (const float*)d_in[11];
    const float* bn2 = (const float*)d_in[12];
    const float* bn3 = (const float*)d_in[13];
    const float* bn4 = (const float*)d_in[14];
    const float* bn5 = (const float*)d_in[15];
    const float* bn6 = (const float*)d_in[16];
    const float* bn7 = (const float*)d_in[17];
    float* outp = (float*)d_out;   // reference outputs are float32

    // workspace carve (floats): xc | ya | yc | gidx | g | h1 | h2 | logits
    float* xc     = (float*)d_ws;
    float* ya     = xc  + (size_t)BB * 512 * NN;
    float* ycb    = ya  + (size_t)BB * 256 * NN;
    int*  gidx    = (int*)(ycb + (size_t)BB * 256 * NN);
    float* g      = (float*)(gidx + (size_t)BB * NN * KK);
    float* h1     = g  + BB * 2 * EMBD;
    float* h2     = h1 + BB * 512;
    float* logits = h2 + BB * 256;

    struct Layer { const float* xin; int C; int bstride; const float* w; const float* bn; int O; float* out; };
    Layer L[4] = {
        { x,            3,   3 * NN,   w1, bn1, 64,  xc            },
        { xc,           64,  512 * NN, w2, bn2, 64,  xc + 64 * NN  },
        { xc + 64 * NN, 64,  512 * NN, w3, bn3, 128, xc + 128 * NN },
        { xc + 128 * NN,128, 512 * NN, w4, bn4, 256, xc + 256 * NN },
    };

    size_t lsz = (size_t)(ROWS * NN) * sizeof(float);   // 32 KB
    for (int i = 0; i < 4; ++i) {
        layer_kernel<<<dim3(BB * 128 + BB * (L[i].O / 8)), dim3(256), lsz, stream>>>(
            L[i].xin, L[i].C, L[i].bstride, L[i].w, L[i].O, gidx, ya, ycb);
        gmax2_kernel<<<dim3(BB * (L[i].O / 2) * 4), dim3(256), 0, stream>>>(ya, ycb, gidx, L[i].bn, L[i].O, L[i].out, 512 * NN);
    }
    emb_kernel<<<dim3(BB * 128), dim3(256), 0, stream>>>(xc, w5, bn5, g);
    head1_naive_kernel<<<dim3(BB * 512), dim3(256), 0, stream>>>(g, l1, bn6, h1);
    head2_naive_kernel<<<dim3(BB * 256), dim3(256), 0, stream>>>(h1, l2w, l2b, bn7, h2);
    head3_naive_kernel<<<dim3(BB * 40), dim3(256), 0, stream>>>(h2, l3w, l3b, logits);
    final_kernel<<<dim3(BB), dim3(64), 0, stream>>>(logits, outp);
}

// Round 19
// 525.103 us; speedup vs baseline: 1.2457x; 1.0231x over previous
//
#include <hip/hip_runtime.h>
#include <hip/hip_bf16.h>
#include <math.h>

#define BB 8
#define NN 1024
#define KK 40
#define EMBD 1024
#define EPSF 1e-5f
#define ROWS 8
#define BBNN (BB * NN)

// 64-bit max with DPP permutation (VALU pipe only; no LDS traffic)
template <int CTRL>
__device__ __forceinline__ unsigned long long dppmax64(unsigned long long cur) {
    unsigned olo = (unsigned)__builtin_amdgcn_update_dpp(0, (int)(unsigned)cur, CTRL, 0xf, 0xf, true);
    unsigned ohi = (unsigned)__builtin_amdgcn_update_dpp(0, (int)(unsigned)(cur >> 32), CTRL, 0xf, 0xf, true);
    unsigned long long o = ((unsigned long long)ohi << 32) | olo;
    return o > cur ? o : cur;
}

// ---------------- fused layer front: knn (blocks 0..BB*128) + yab (rest); b = blk&7 (XCD-local) ----------------
__global__ __launch_bounds__(256) void layer_kernel(const float* __restrict__ x, int C, int bstride,
                                                    const float* __restrict__ w, int O,
                                                    int* __restrict__ gidx,
                                                    float* __restrict__ ya, float* __restrict__ yc) {
    extern __shared__ float lds[];
    int tid = threadIdx.x;

    if (blockIdx.x < BB * 128) {
        // ================= knn role =================
        float* S = lds;                  // ROWS*NN = 32 KB
        int b = blockIdx.x & 7;          // XCD-local batch
        int n0 = ((blockIdx.x >> 3) & 127) * ROWS;
        const float* xb = x + (size_t)b * bstride;

        float acc[ROWS][4];
        float xxa[4] = {0.f, 0.f, 0.f, 0.f};
#pragma unroll
        for (int r = 0; r < ROWS; ++r)
#pragma unroll
            for (int j = 0; j < 4; ++j) acc[r][j] = 0.f;

        for (int c = 0; c < C; ++c) {
            float4 xm  = *(const float4*)&xb[c * NN + (tid << 2)];
            float4 ce0 = *(const float4*)&xb[c * NN + n0];        // wave-uniform -> s_load
            float4 ce1 = *(const float4*)&xb[c * NN + n0 + 4];
            xxa[0] = fmaf(xm.x, xm.x, xxa[0]);
            xxa[1] = fmaf(xm.y, xm.y, xxa[1]);
            xxa[2] = fmaf(xm.z, xm.z, xxa[2]);
            xxa[3] = fmaf(xm.w, xm.w, xxa[3]);
            float ce[8] = {ce0.x, ce0.y, ce0.z, ce0.w, ce1.x, ce1.y, ce1.z, ce1.w};
#pragma unroll
            for (int r = 0; r < ROWS; ++r) {
                acc[r][0] = fmaf(ce[r], xm.x, acc[r][0]);
                acc[r][1] = fmaf(ce[r], xm.y, acc[r][1]);
                acc[r][2] = fmaf(ce[r], xm.z, acc[r][2]);
                acc[r][3] = fmaf(ce[r], xm.w, acc[r][3]);
            }
        }
#pragma unroll
        for (int r = 0; r < ROWS; ++r) {
            float4 sv;
            sv.x = 2.f * acc[r][0] - xxa[0];
            sv.y = 2.f * acc[r][1] - xxa[1];
            sv.z = 2.f * acc[r][2] - xxa[2];
            sv.w = 2.f * acc[r][3] - xxa[3];
            *(float4*)&S[r * NN + (tid << 2)] = sv;
        }
        __syncthreads();

        // ---- selection: 2 rows/wave; packed-key bitonic sort + DPP pop-head tournament ----
        int wave = tid >> 6, lane = tid & 63;
        int ra = wave << 1, rb = ra + 1;
        unsigned long long va[16], vb[16];
#pragma unroll
        for (int j = 0; j < 16; ++j) {
            unsigned ua = __float_as_uint(S[ra * NN + lane + 64 * j]);
            unsigned ub = __float_as_uint(S[rb * NN + lane + 64 * j]);
            ua ^= (unsigned)((int)ua >> 31) | 0x80000000u;      // monotone float->uint
            ub ^= (unsigned)((int)ub >> 31) | 0x80000000u;
            unsigned lo = (unsigned)(1023 - (lane + (j << 6))); // tie -> min index wins
            va[j] = ((unsigned long long)ua << 32) | lo;
            vb[j] = ((unsigned long long)ub << 32) | lo;
        }
        // bitonic sort ascending: va[15] = lane max
#pragma unroll
        for (int k = 2; k <= 16; k <<= 1)
#pragma unroll
        for (int s = k >> 1; s > 0; s >>= 1)
#pragma unroll
        for (int i = 0; i < 16; ++i) {
            int l = i ^ s;
            if (l > i) {
                bool up = ((i & k) == 0);
                { unsigned long long A = va[i], B = va[l];
                  bool sw = up ? (A > B) : (A < B);
                  va[i] = sw ? B : A; va[l] = sw ? A : B; }
                { unsigned long long A = vb[i], B = vb[l];
                  bool sw = up ? (A > B) : (A < B);
                  vb[i] = sw ? B : A; vb[l] = sw ? A : B; }
            }
        }
        int* ga = gidx + (size_t)b * NN + n0 + ra;
        int* gb = gidx + (size_t)b * NN + n0 + rb;
        unsigned long long ha = va[15], hb = vb[15];
        for (int it = 0; it < KK; ++it) {
            unsigned long long ma = ha, mb = hb;
            ma = dppmax64<0x111>(ma); mb = dppmax64<0x111>(mb);   // row_shr:1
            ma = dppmax64<0x112>(ma); mb = dppmax64<0x112>(mb);   // row_shr:2
            ma = dppmax64<0x114>(ma); mb = dppmax64<0x114>(mb);   // row_shr:4
            ma = dppmax64<0x118>(ma); mb = dppmax64<0x118>(mb);   // row_shr:8
            ma = dppmax64<0x142>(ma); mb = dppmax64<0x142>(mb);   // row_bcast15
            ma = dppmax64<0x143>(ma); mb = dppmax64<0x143>(mb);   // row_bcast31 -> lane63 = max
            unsigned wla = (unsigned)__builtin_amdgcn_readlane((int)(unsigned)ma, 63);
            unsigned wha = (unsigned)__builtin_amdgcn_readlane((int)(unsigned)(ma >> 32), 63);
            unsigned wlb = (unsigned)__builtin_amdgcn_readlane((int)(unsigned)mb, 63);
            unsigned whb = (unsigned)__builtin_amdgcn_readlane((int)(unsigned)(mb >> 32), 63);
            if (lane == 0) {
                ga[(size_t)it * BBNN] = 1023 - (int)wla;
                gb[(size_t)it * BBNN] = 1023 - (int)wlb;
            }
            unsigned long long wka = ((unsigned long long)wha << 32) | wla;
            unsigned long long wkb = ((unsigned long long)whb << 32) | wlb;
            bool pa = (ha == wka), pb = (hb == wkb);   // unique keys: exactly one lane pops
#pragma unroll
            for (int j = 15; j > 0; --j) {
                va[j] = pa ? va[j - 1] : va[j];
                vb[j] = pb ? vb[j - 1] : vb[j];
            }
            va[0] = pa ? 0ull : va[0];
            vb[0] = pb ? 0ull : vb[0];
            ha = va[15]; hb = vb[15];
        }
    } else {
        // ================= yab role =================
        int bid = blockIdx.x - BB * 128;
        float* wls = lds;                // [8*C] wa, then [8*C] wc
        int b  = bid & 7;                // XCD-local batch
        int o0 = (bid >> 3) << 3;
        const float* xb = x + (size_t)b * bstride;

        for (int t = tid; t < 8 * C; t += 256) {
            int r = t / C, c = t - r * C;
            float wa = w[(size_t)(o0 + r) * 2 * C + c];
            float wb = w[(size_t)(o0 + r) * 2 * C + C + c];
            wls[t] = wa;
            wls[8 * C + t] = wb - wa;
        }
        __syncthreads();

        float a[8][4], cv[8][4];
#pragma unroll
        for (int r = 0; r < 8; ++r)
#pragma unroll
            for (int j = 0; j < 4; ++j) { a[r][j] = 0.f; cv[r][j] = 0.f; }
        for (int c = 0; c < C; ++c) {
            float4 xm = *(const float4*)&xb[c * NN + (tid << 2)];
#pragma unroll
            for (int r = 0; r < 8; ++r) {
                float wa = wls[r * C + c];
                float wc = wls[8 * C + r * C + c];
                a[r][0]  = fmaf(wa, xm.x, a[r][0]);  cv[r][0] = fmaf(wc, xm.x, cv[r][0]);
                a[r][1]  = fmaf(wa, xm.y, a[r][1]);  cv[r][1] = fmaf(wc, xm.y, cv[r][1]);
                a[r][2]  = fmaf(wa, xm.z, a[r][2]);  cv[r][2] = fmaf(wc, xm.z, cv[r][2]);
                a[r][3]  = fmaf(wa, xm.w, a[r][3]);  cv[r][3] = fmaf(wc, xm.w, cv[r][3]);
            }
        }
#pragma unroll
        for (int r = 0; r < 8; ++r) {
            size_t off = ((size_t)b * O + o0 + r) * NN + (tid << 2);
            *(float4*)&ya[off] = *(float4*)&a[r][0];
            *(float4*)&yc[off] = *(float4*)&cv[r][0];
        }
    }
}

// ---------------- gmax2: 2 o-rows per block; b = blk&7 (XCD-local) ----------------
__global__ __launch_bounds__(256) void gmax2_kernel(const float* __restrict__ ya, const float* __restrict__ yc,
                                                    const int* __restrict__ gidx, const float* __restrict__ bnp,
                                                    int O, float* __restrict__ outp, int out_bstride) {
    __shared__ float yrow[2 * NN];       // 8 KB
    int tid = threadIdx.x;
    int b    = blockIdx.x & 7;           // XCD-local batch
    int rest = blockIdx.x >> 3;
    int opb = O >> 1;
    int oc = rest % opb;
    int nt = rest / opb;                 // 0..3
    int o0 = oc << 1;
    int n  = (nt << 8) + tid;

    const float4* src = (const float4*)(ya + ((size_t)b * O + o0) * NN);
#pragma unroll
    for (int i = 0; i < 2; ++i)
        ((float4*)yrow)[tid + (i << 8)] = src[tid + (i << 8)];
    __syncthreads();

    int idx[KK];
    const int* gi = gidx + (size_t)b * NN + n;
#pragma unroll
    for (int k = 0; k < KK; ++k) idx[k] = gi[(size_t)k * BBNN];

    float m0 = -INFINITY, m1 = -INFINITY;
#pragma unroll 8
    for (int k = 0; k < KK; ++k) {
        int j = idx[k];
        m0 = fmaxf(m0, yrow[j]);
        m1 = fmaxf(m1, yrow[NN + j]);
    }
    m0 += yc[((size_t)b * O + o0 + 0) * NN + n];
    m1 += yc[((size_t)b * O + o0 + 1) * NN + n];
    {
        int o = o0;
        float sc = bnp[o] * rsqrtf(bnp[3 * O + o] + EPSF);
        float t0 = (m0 - bnp[2 * O + o]) * sc + bnp[O + o];
        outp[(size_t)b * out_bstride + (size_t)o * NN + n] = t0 >= 0.f ? t0 : 0.2f * t0;
    }
    {
        int o = o0 + 1;
        float sc = bnp[o] * rsqrtf(bnp[3 * O + o] + EPSF);
        float t0 = (m1 - bnp[2 * O + o]) * sc + bnp[O + o];
        outp[(size_t)b * out_bstride + (size_t)o * NN + n] = t0 >= 0.f ? t0 : 0.2f * t0;
    }
}

// ---------------- emb v7: XCD-local, SGPR w5, 8o x 4n, unroll 4 ----------------
__global__ __launch_bounds__(256) void emb_kernel(const float* __restrict__ xc, const float* __restrict__ w5,
                                                  const float* __restrict__ bnp, float* __restrict__ g) {
    __shared__ float rmax[8][4], rsum[8][4];
    int tid = threadIdx.x;
    int b  = blockIdx.x & 7;             // XCD-local batches
    int o0 = (blockIdx.x >> 3) << 3;     // 128 o-blocks of 8
    const float* xcb = xc + (size_t)b * 512 * NN;
    const float* wr  = w5 + (size_t)o0 * 512;

    int n4 = tid << 2;
    float acc[8][4];
#pragma unroll
    for (int r = 0; r < 8; ++r)
#pragma unroll
        for (int j = 0; j < 4; ++j) acc[r][j] = 0.f;

#pragma unroll 4
    for (int c4 = 0; c4 < 128; ++c4) {
        int c = c4 << 2;
        float4 xm0 = *(const float4*)&xcb[(c + 0) * NN + n4];
        float4 xm1 = *(const float4*)&xcb[(c + 1) * NN + n4];
        float4 xm2 = *(const float4*)&xcb[(c + 2) * NN + n4];
        float4 xm3 = *(const float4*)&xcb[(c + 3) * NN + n4];
#pragma unroll
        for (int r = 0; r < 8; ++r) {
            float4 wv = *(const float4*)&wr[r * 512 + c];   // uniform addr -> s_load_dwordx4
            acc[r][0] = fmaf(wv.x, xm0.x, acc[r][0]);
            acc[r][1] = fmaf(wv.x, xm0.y, acc[r][1]);
            acc[r][2] = fmaf(wv.x, xm0.z, acc[r][2]);
            acc[r][3] = fmaf(wv.x, xm0.w, acc[r][3]);
            acc[r][0] = fmaf(wv.y, xm1.x, acc[r][0]);
            acc[r][1] = fmaf(wv.y, xm1.y, acc[r][1]);
            acc[r][2] = fmaf(wv.y, xm1.z, acc[r][2]);
            acc[r][3] = fmaf(wv.y, xm1.w, acc[r][3]);
            acc[r][0] = fmaf(wv.z, xm2.x, acc[r][0]);
            acc[r][1] = fmaf(wv.z, xm2.y, acc[r][1]);
            acc[r][2] = fmaf(wv.z, xm2.z, acc[r][2]);
            acc[r][3] = fmaf(wv.z, xm2.w, acc[r][3]);
            acc[r][0] = fmaf(wv.w, xm3.x, acc[r][0]);
            acc[r][1] = fmaf(wv.w, xm3.y, acc[r][1]);
            acc[r][2] = fmaf(wv.w, xm3.z, acc[r][2]);
            acc[r][3] = fmaf(wv.w, xm3.w, acc[r][3]);
        }
    }

    int lane = tid & 63, wave = tid >> 6;
#pragma unroll
    for (int r = 0; r < 8; ++r) {
        int o = o0 + r;
        float sc = bnp[o] * rsqrtf(bnp[3 * EMBD + o] + EPSF);
        float mu = bnp[2 * EMBD + o], be = bnp[EMBD + o];
        float vmax = -INFINITY, vsum = 0.f;
#pragma unroll
        for (int j = 0; j < 4; ++j) {
            float t0 = (acc[r][j] - mu) * sc + be;
            t0 = t0 >= 0.f ? t0 : 0.2f * t0;
            vmax = fmaxf(vmax, t0);
            vsum += t0;
        }
#pragma unroll
        for (int off = 32; off >= 1; off >>= 1) {
            vmax = fmaxf(vmax, __shfl_xor(vmax, off));
            vsum += __shfl_xor(vsum, off);
        }
        if (lane == 0) { rmax[r][wave] = vmax; rsum[r][wave] = vsum; }
    }
    __syncthreads();
    if (tid < 8) {
        float vm = fmaxf(fmaxf(rmax[tid][0], rmax[tid][1]), fmaxf(rmax[tid][2], rmax[tid][3]));
        g[(size_t)b * 2 * EMBD + o0 + tid] = vm;
    } else if (tid < 16) {
        int r = tid - 8;
        float vs = rsum[r][0] + rsum[r][1] + rsum[r][2] + rsum[r][3];
        g[(size_t)b * 2 * EMBD + EMBD + o0 + r] = vs * (1.0f / 1024.0f);
    }
}

// ---------------- naive head1: one block per (b,o) ----------------
__global__ __launch_bounds__(256) void head1_naive_kernel(const float* __restrict__ g, const float* __restrict__ l1,
                                                          const float* __restrict__ bnp, float* __restrict__ h1) {
    __shared__ float red[256];
    int tid = threadIdx.x;
    int b = blockIdx.x >> 9, o = blockIdx.x & 511;
    const float* gr = g + (size_t)b * 2 * EMBD;
    const float* lr = l1 + (size_t)o * 2 * EMBD;
    float s = 0.f;
    for (int c = tid; c < 2048; c += 256) s = fmaf(gr[c], lr[c], s);
    red[tid] = s;
    __syncthreads();
    for (int st = 128; st >= 1; st >>= 1) {
        if (tid < st) red[tid] += red[tid + st];
        __syncthreads();
    }
    if (tid == 0) {
        float sc = bnp[o] * rsqrtf(bnp[3 * 512 + o] + EPSF);
        float t0 = (red[0] - bnp[2 * 512 + o]) * sc + bnp[512 + o];
        h1[b * 512 + o] = t0 >= 0.f ? t0 : 0.2f * t0;
    }
}

// ---------------- naive head2: one block per (b,o) ----------------
__global__ __launch_bounds__(256) void head2_naive_kernel(const float* __restrict__ h1, const float* __restrict__ l2w,
                                                          const float* __restrict__ l2b, const float* __restrict__ bnp,
                                                          float* __restrict__ h2) {
    __shared__ float red[256];
    int tid = threadIdx.x;
    int b = blockIdx.x >> 8, o = blockIdx.x & 255;
    const float* hr = h1 + (size_t)b * 512;
    const float* lr = l2w + (size_t)o * 512;
    float s = fmaf(hr[tid], lr[tid], hr[tid + 256] * lr[tid + 256]);
    red[tid] = s;
    __syncthreads();
    for (int st = 128; st >= 1; st >>= 1) {
        if (tid < st) red[tid] += red[tid + st];
        __syncthreads();
    }
    if (tid == 0) {
        float v = red[0] + l2b[o];
        float sc = bnp[o] * rsqrtf(bnp[3 * 256 + o] + EPSF);
        float t0 = (v - bnp[2 * 256 + o]) * sc + bnp[256 + o];
        h2[b * 256 + o] = t0 >= 0.f ? t0 : 0.2f * t0;
    }
}

// ---------------- naive head3: one block per (b,i) -> logits scratch ----------------
__global__ __launch_bounds__(256) void head3_naive_kernel(const float* __restrict__ h2, const float* __restrict__ l3w,
                                                          const float* __restrict__ l3b, float* __restrict__ logits) {
    __shared__ float red[256];
    int tid = threadIdx.x;
    int b = blockIdx.x / 40, i = blockIdx.x % 40;
    red[tid] = h2[(size_t)b * 256 + tid] * l3w[(size_t)i * 256 + tid];
    __syncthreads();
    for (int st = 128; st >= 1; st >>= 1) {
        if (tid < st) red[tid] += red[tid + st];
        __syncthreads();
    }
    if (tid == 0) logits[b * 40 + i] = red[0] + l3b[i];
}

// ---------------- final: out[0..319]=logits (f32), out[320..639]=log_softmax (f32) ----------------
__global__ void final_kernel(const float* __restrict__ logits, float* __restrict__ outp) {
    int b = blockIdx.x;
    if (threadIdx.x != 0) return;
    const float* lr = logits + b * 40;
    float mx = lr[0];
    for (int i = 1; i < 40; ++i) mx = fmaxf(mx, lr[i]);
    float se = 0.f;
    for (int i = 0; i < 40; ++i) se += expf(lr[i] - mx);
    float lse = logf(se);
    for (int i = 0; i < 40; ++i) {
        outp[b * 40 + i]            = lr[i];
        outp[BB * 40 + b * 40 + i]  = lr[i] - mx - lse;
    }
}

extern "C" void kernel_launch(void* const* d_in, const int* in_sizes, int n_in,
                              void* d_out, int out_size, void* d_ws, size_t ws_size,
                              hipStream_t stream) {
    const float* x   = (const float*)d_in[0];
    const float* w1  = (const float*)d_in[1];
    const float* w2  = (const float*)d_in[2];
    const float* w3  = (const float*)d_in[3];
    const float* w4  = (const float*)d_in[4];
    const float* w5  = (const float*)d_in[5];
    const float* l1  = (const float*)d_in[6];
    const float* l2w = (const float*)d_in[7];
    const float* l2b = (const float*)d_in[8];
    const float* l3w = (const float*)d_in[9];
    const float* l3b = (const float*)d_in[10];
    const float* bn1 = (const float*)d_in[11];
    const float* bn2 = (const float*)d_in[12];
    const float* bn3 = (const float*)d_in[13];
    const float* bn4 = (const float*)d_in[14];
    const float* bn5 = (const float*)d_in[15];
    const float* bn6 = (const float*)d_in[16];
    const float* bn7 = (const float*)d_in[17];
    float* outp = (float*)d_out;   // reference outputs are float32

    // workspace carve (floats): xc | ya | yc | gidx | g | h1 | h2 | logits
    float* xc     = (float*)d_ws;
    float* ya     = xc  + (size_t)BB * 512 * NN;
    float* ycb    = ya  + (size_t)BB * 256 * NN;
    int*  gidx    = (int*)(ycb + (size_t)BB * 256 * NN);
    float* g      = (float*)(gidx + (size_t)BB * NN * KK);
    float* h1     = g  + BB * 2 * EMBD;
    float* h2     = h1 + BB * 512;
    float* logits = h2 + BB * 256;

    struct Layer { const float* xin; int C; int bstride; const float* w; const float* bn; int O; float* out; };
    Layer L[4] = {
        { x,            3,   3 * NN,   w1, bn1, 64,  xc            },
        { xc,           64,  512 * NN, w2, bn2, 64,  xc + 64 * NN  },
        { xc + 64 * NN, 64,  512 * NN, w3, bn3, 128, xc + 128 * NN },
        { xc + 128 * NN,128, 512 * NN, w4, bn4, 256, xc + 256 * NN },
    };

    size_t lsz = (size_t)(ROWS * NN) * sizeof(float);   // 32 KB
    for (int i = 0; i < 4; ++i) {
        layer_kernel<<<dim3(BB * 128 + BB * (L[i].O / 8)), dim3(256), lsz, stream>>>(
            L[i].xin, L[i].C, L[i].bstride, L[i].w, L[i].O, gidx, ya, ycb);
        gmax2_kernel<<<dim3(BB * (L[i].O / 2) * 4), dim3(256), 0, stream>>>(ya, ycb, gidx, L[i].bn, L[i].O, L[i].out, 512 * NN);
    }
    emb_kernel<<<dim3(BB * 128), dim3(256), 0, stream>>>(xc, w5, bn5, g);
    head1_naive_kernel<<<dim3(BB * 512), dim3(256), 0, stream>>>(g, l1, bn6, h1);
    head2_naive_kernel<<<dim3(BB * 256), dim3(256), 0, stream>>>(h1, l2w, l2b, bn7, h2);
    head3_naive_kernel<<<dim3(BB * 40), dim3(256), 0, stream>>>(h2, l3w, l3b, logits);
    final_kernel<<<dim3(BB), dim3(64), 0, stream>>>(logits, outp);
}

// Round 20
// 520.446 us; speedup vs baseline: 1.2568x; 1.0089x over previous
//
#include <hip/hip_runtime.h>
#include <hip/hip_bf16.h>
#include <math.h>

#define BB 8
#define NN 1024
#define KK 40
#define EMBD 1024
#define EPSF 1e-5f
#define ROWS 8
#define BBNN (BB * NN)

// 64-bit max with DPP permutation (VALU pipe only; no LDS traffic)
template <int CTRL>
__device__ __forceinline__ unsigned long long dppmax64(unsigned long long cur) {
    unsigned olo = (unsigned)__builtin_amdgcn_update_dpp(0, (int)(unsigned)cur, CTRL, 0xf, 0xf, true);
    unsigned ohi = (unsigned)__builtin_amdgcn_update_dpp(0, (int)(unsigned)(cur >> 32), CTRL, 0xf, 0xf, true);
    unsigned long long o = ((unsigned long long)ohi << 32) | olo;
    return o > cur ? o : cur;
}

// ---------------- fused layer front: knn (blocks 0..BB*128) + yab (rest); b = blk&7 (XCD-local) ----------------
__global__ __launch_bounds__(256) void layer_kernel(const float* __restrict__ x, int C, int bstride,
                                                    const float* __restrict__ w, int O,
                                                    int* __restrict__ gidx,
                                                    float* __restrict__ ya, float* __restrict__ yc) {
    extern __shared__ float lds[];
    int tid = threadIdx.x;

    if (blockIdx.x < BB * 128) {
        // ================= knn role =================
        float* S = lds;                  // ROWS*NN = 32 KB
        int b = blockIdx.x & 7;          // XCD-local batch
        int n0 = ((blockIdx.x >> 3) & 127) * ROWS;
        const float* xb = x + (size_t)b * bstride;

        float acc[ROWS][4];
        float xxa[4] = {0.f, 0.f, 0.f, 0.f};
#pragma unroll
        for (int r = 0; r < ROWS; ++r)
#pragma unroll
            for (int j = 0; j < 4; ++j) acc[r][j] = 0.f;

        for (int c = 0; c < C; ++c) {
            float4 xm  = *(const float4*)&xb[c * NN + (tid << 2)];
            float4 ce0 = *(const float4*)&xb[c * NN + n0];        // wave-uniform -> s_load
            float4 ce1 = *(const float4*)&xb[c * NN + n0 + 4];
            xxa[0] = fmaf(xm.x, xm.x, xxa[0]);
            xxa[1] = fmaf(xm.y, xm.y, xxa[1]);
            xxa[2] = fmaf(xm.z, xm.z, xxa[2]);
            xxa[3] = fmaf(xm.w, xm.w, xxa[3]);
            float ce[8] = {ce0.x, ce0.y, ce0.z, ce0.w, ce1.x, ce1.y, ce1.z, ce1.w};
#pragma unroll
            for (int r = 0; r < ROWS; ++r) {
                acc[r][0] = fmaf(ce[r], xm.x, acc[r][0]);
                acc[r][1] = fmaf(ce[r], xm.y, acc[r][1]);
                acc[r][2] = fmaf(ce[r], xm.z, acc[r][2]);
                acc[r][3] = fmaf(ce[r], xm.w, acc[r][3]);
            }
        }
#pragma unroll
        for (int r = 0; r < ROWS; ++r) {
            float4 sv;
            sv.x = 2.f * acc[r][0] - xxa[0];
            sv.y = 2.f * acc[r][1] - xxa[1];
            sv.z = 2.f * acc[r][2] - xxa[2];
            sv.w = 2.f * acc[r][3] - xxa[3];
            *(float4*)&S[r * NN + (tid << 2)] = sv;
        }
        __syncthreads();

        // ---- selection: 2 rows/wave; packed-key bitonic sort + DPP pop-head tournament ----
        int wave = tid >> 6, lane = tid & 63;
        int ra = wave << 1, rb = ra + 1;
        unsigned long long va[16], vb[16];
#pragma unroll
        for (int j = 0; j < 16; ++j) {
            unsigned ua = __float_as_uint(S[ra * NN + lane + 64 * j]);
            unsigned ub = __float_as_uint(S[rb * NN + lane + 64 * j]);
            ua ^= (unsigned)((int)ua >> 31) | 0x80000000u;      // monotone float->uint
            ub ^= (unsigned)((int)ub >> 31) | 0x80000000u;
            unsigned lo = (unsigned)(1023 - (lane + (j << 6))); // tie -> min index wins
            va[j] = ((unsigned long long)ua << 32) | lo;
            vb[j] = ((unsigned long long)ub << 32) | lo;
        }
        // bitonic sort ascending: va[15] = lane max
#pragma unroll
        for (int k = 2; k <= 16; k <<= 1)
#pragma unroll
        for (int s = k >> 1; s > 0; s >>= 1)
#pragma unroll
        for (int i = 0; i < 16; ++i) {
            int l = i ^ s;
            if (l > i) {
                bool up = ((i & k) == 0);
                { unsigned long long A = va[i], B = va[l];
                  bool sw = up ? (A > B) : (A < B);
                  va[i] = sw ? B : A; va[l] = sw ? A : B; }
                { unsigned long long A = vb[i], B = vb[l];
                  bool sw = up ? (A > B) : (A < B);
                  vb[i] = sw ? B : A; vb[l] = sw ? A : B; }
            }
        }
        int* ga = gidx + (size_t)b * NN + n0 + ra;
        int* gb = gidx + (size_t)b * NN + n0 + rb;
        unsigned long long ha = va[15], hb = vb[15];
        for (int it = 0; it < KK; ++it) {
            unsigned long long ma = ha, mb = hb;
            ma = dppmax64<0x111>(ma); mb = dppmax64<0x111>(mb);   // row_shr:1
            ma = dppmax64<0x112>(ma); mb = dppmax64<0x112>(mb);   // row_shr:2
            ma = dppmax64<0x114>(ma); mb = dppmax64<0x114>(mb);   // row_shr:4
            ma = dppmax64<0x118>(ma); mb = dppmax64<0x118>(mb);   // row_shr:8
            ma = dppmax64<0x142>(ma); mb = dppmax64<0x142>(mb);   // row_bcast15
            ma = dppmax64<0x143>(ma); mb = dppmax64<0x143>(mb);   // row_bcast31 -> lane63 = max
            unsigned wla = (unsigned)__builtin_amdgcn_readlane((int)(unsigned)ma, 63);
            unsigned wha = (unsigned)__builtin_amdgcn_readlane((int)(unsigned)(ma >> 32), 63);
            unsigned wlb = (unsigned)__builtin_amdgcn_readlane((int)(unsigned)mb, 63);
            unsigned whb = (unsigned)__builtin_amdgcn_readlane((int)(unsigned)(mb >> 32), 63);
            if (lane == 0) {
                ga[(size_t)it * BBNN] = 1023 - (int)wla;
                gb[(size_t)it * BBNN] = 1023 - (int)wlb;
            }
            unsigned long long wka = ((unsigned long long)wha << 32) | wla;
            unsigned long long wkb = ((unsigned long long)whb << 32) | wlb;
            bool pa = (ha == wka), pb = (hb == wkb);   // unique keys: exactly one lane pops
#pragma unroll
            for (int j = 15; j > 0; --j) {
                va[j] = pa ? va[j - 1] : va[j];
                vb[j] = pb ? vb[j - 1] : vb[j];
            }
            va[0] = pa ? 0ull : va[0];
            vb[0] = pb ? 0ull : vb[0];
            ha = va[15]; hb = vb[15];
        }
    } else {
        // ================= yab role =================
        int bid = blockIdx.x - BB * 128;
        float* wls = lds;                // [8*C] wa, then [8*C] wc
        int b  = bid & 7;                // XCD-local batch
        int o0 = (bid >> 3) << 3;
        const float* xb = x + (size_t)b * bstride;

        for (int t = tid; t < 8 * C; t += 256) {
            int r = t / C, c = t - r * C;
            float wa = w[(size_t)(o0 + r) * 2 * C + c];
            float wb = w[(size_t)(o0 + r) * 2 * C + C + c];
            wls[t] = wa;
            wls[8 * C + t] = wb - wa;
        }
        __syncthreads();

        float a[8][4], cv[8][4];
#pragma unroll
        for (int r = 0; r < 8; ++r)
#pragma unroll
            for (int j = 0; j < 4; ++j) { a[r][j] = 0.f; cv[r][j] = 0.f; }
        for (int c = 0; c < C; ++c) {
            float4 xm = *(const float4*)&xb[c * NN + (tid << 2)];
#pragma unroll
            for (int r = 0; r < 8; ++r) {
                float wa = wls[r * C + c];
                float wc = wls[8 * C + r * C + c];
                a[r][0]  = fmaf(wa, xm.x, a[r][0]);  cv[r][0] = fmaf(wc, xm.x, cv[r][0]);
                a[r][1]  = fmaf(wa, xm.y, a[r][1]);  cv[r][1] = fmaf(wc, xm.y, cv[r][1]);
                a[r][2]  = fmaf(wa, xm.z, a[r][2]);  cv[r][2] = fmaf(wc, xm.z, cv[r][2]);
                a[r][3]  = fmaf(wa, xm.w, a[r][3]);  cv[r][3] = fmaf(wc, xm.w, cv[r][3]);
            }
        }
#pragma unroll
        for (int r = 0; r < 8; ++r) {
            size_t off = ((size_t)b * O + o0 + r) * NN + (tid << 2);
            *(float4*)&ya[off] = *(float4*)&a[r][0];
            *(float4*)&yc[off] = *(float4*)&cv[r][0];
        }
    }
}

// ---------------- gmax2: 2 o-rows per block; b = blk&7 (XCD-local) ----------------
__global__ __launch_bounds__(256) void gmax2_kernel(const float* __restrict__ ya, const float* __restrict__ yc,
                                                    const int* __restrict__ gidx, const float* __restrict__ bnp,
                                                    int O, float* __restrict__ outp, int out_bstride) {
    __shared__ float yrow[2 * NN];       // 8 KB
    int tid = threadIdx.x;
    int b    = blockIdx.x & 7;           // XCD-local batch
    int rest = blockIdx.x >> 3;
    int opb = O >> 1;
    int oc = rest % opb;
    int nt = rest / opb;                 // 0..3
    int o0 = oc << 1;
    int n  = (nt << 8) + tid;

    const float4* src = (const float4*)(ya + ((size_t)b * O + o0) * NN);
#pragma unroll
    for (int i = 0; i < 2; ++i)
        ((float4*)yrow)[tid + (i << 8)] = src[tid + (i << 8)];
    __syncthreads();

    int idx[KK];
    const int* gi = gidx + (size_t)b * NN + n;
#pragma unroll
    for (int k = 0; k < KK; ++k) idx[k] = gi[(size_t)k * BBNN];

    float m0 = -INFINITY, m1 = -INFINITY;
#pragma unroll 8
    for (int k = 0; k < KK; ++k) {
        int j = idx[k];
        m0 = fmaxf(m0, yrow[j]);
        m1 = fmaxf(m1, yrow[NN + j]);
    }
    m0 += yc[((size_t)b * O + o0 + 0) * NN + n];
    m1 += yc[((size_t)b * O + o0 + 1) * NN + n];
    {
        int o = o0;
        float sc = bnp[o] * rsqrtf(bnp[3 * O + o] + EPSF);
        float t0 = (m0 - bnp[2 * O + o]) * sc + bnp[O + o];
        outp[(size_t)b * out_bstride + (size_t)o * NN + n] = t0 >= 0.f ? t0 : 0.2f * t0;
    }
    {
        int o = o0 + 1;
        float sc = bnp[o] * rsqrtf(bnp[3 * O + o] + EPSF);
        float t0 = (m1 - bnp[2 * O + o]) * sc + bnp[O + o];
        outp[(size_t)b * out_bstride + (size_t)o * NN + n] = t0 >= 0.f ? t0 : 0.2f * t0;
    }
}

// ---------------- emb v8: 128-thread blocks, n-half split, SGPR w5, 8o x 4n ----------------
__global__ __launch_bounds__(128) void emb_part_kernel(const float* __restrict__ xc, const float* __restrict__ w5,
                                                       const float* __restrict__ bnp,
                                                       float* __restrict__ pmax, float* __restrict__ psum) {
    __shared__ float rmax[8][2], rsum[8][2];
    int tid = threadIdx.x;               // 0..127
    int b    = blockIdx.x & 7;           // XCD-local batches
    int rest = blockIdx.x >> 3;          // 0..255
    int ot = rest >> 1;                  // o-tile 0..127
    int h  = rest & 1;                   // n-half
    int o0 = ot << 3;
    const float* xcb = xc + (size_t)b * 512 * NN + (h << 9);
    const float* wr  = w5 + (size_t)o0 * 512;

    int n4 = tid << 2;                   // 0..508 within half
    float acc[8][4];
#pragma unroll
    for (int r = 0; r < 8; ++r)
#pragma unroll
        for (int j = 0; j < 4; ++j) acc[r][j] = 0.f;

#pragma unroll 2
    for (int c4 = 0; c4 < 128; ++c4) {
        int c = c4 << 2;
        float4 xm0 = *(const float4*)&xcb[(c + 0) * NN + n4];
        float4 xm1 = *(const float4*)&xcb[(c + 1) * NN + n4];
        float4 xm2 = *(const float4*)&xcb[(c + 2) * NN + n4];
        float4 xm3 = *(const float4*)&xcb[(c + 3) * NN + n4];
#pragma unroll
        for (int r = 0; r < 8; ++r) {
            float4 wv = *(const float4*)&wr[r * 512 + c];   // uniform addr -> s_load_dwordx4
            acc[r][0] = fmaf(wv.x, xm0.x, acc[r][0]);
            acc[r][1] = fmaf(wv.x, xm0.y, acc[r][1]);
            acc[r][2] = fmaf(wv.x, xm0.z, acc[r][2]);
            acc[r][3] = fmaf(wv.x, xm0.w, acc[r][3]);
            acc[r][0] = fmaf(wv.y, xm1.x, acc[r][0]);
            acc[r][1] = fmaf(wv.y, xm1.y, acc[r][1]);
            acc[r][2] = fmaf(wv.y, xm1.z, acc[r][2]);
            acc[r][3] = fmaf(wv.y, xm1.w, acc[r][3]);
            acc[r][0] = fmaf(wv.z, xm2.x, acc[r][0]);
            acc[r][1] = fmaf(wv.z, xm2.y, acc[r][1]);
            acc[r][2] = fmaf(wv.z, xm2.z, acc[r][2]);
            acc[r][3] = fmaf(wv.z, xm2.w, acc[r][3]);
            acc[r][0] = fmaf(wv.w, xm3.x, acc[r][0]);
            acc[r][1] = fmaf(wv.w, xm3.y, acc[r][1]);
            acc[r][2] = fmaf(wv.w, xm3.z, acc[r][2]);
            acc[r][3] = fmaf(wv.w, xm3.w, acc[r][3]);
        }
    }

    int lane = tid & 63, wave = tid >> 6;   // 2 waves
#pragma unroll
    for (int r = 0; r < 8; ++r) {
        int o = o0 + r;
        float sc = bnp[o] * rsqrtf(bnp[3 * EMBD + o] + EPSF);
        float mu = bnp[2 * EMBD + o], be = bnp[EMBD + o];
        float vmax = -INFINITY, vsum = 0.f;
#pragma unroll
        for (int j = 0; j < 4; ++j) {
            float t0 = (acc[r][j] - mu) * sc + be;
            t0 = t0 >= 0.f ? t0 : 0.2f * t0;
            vmax = fmaxf(vmax, t0);
            vsum += t0;
        }
#pragma unroll
        for (int off = 32; off >= 1; off >>= 1) {
            vmax = fmaxf(vmax, __shfl_xor(vmax, off));
            vsum += __shfl_xor(vsum, off);
        }
        if (lane == 0) { rmax[r][wave] = vmax; rsum[r][wave] = vsum; }
    }
    __syncthreads();
    size_t base = (((size_t)b * 128 + ot) * 2 + h) * 8;
    if (tid < 8) {
        pmax[base + tid] = fmaxf(rmax[tid][0], rmax[tid][1]);
    } else if (tid < 16) {
        int r = tid - 8;
        psum[base + r] = rsum[r][0] + rsum[r][1];
    }
}

// ---------------- emb combine: halves -> g ----------------
__global__ __launch_bounds__(256) void emb_comb_kernel(const float* __restrict__ pmax, const float* __restrict__ psum,
                                                       float* __restrict__ g) {
    int i = blockIdx.x * 256 + threadIdx.x;   // 8192
    int b = i >> 10, o = i & 1023;
    int ot = o >> 3, r = o & 7;
    size_t base = (((size_t)b * 128 + ot) * 2) * 8 + r;
    g[(size_t)b * 2 * EMBD + o]        = fmaxf(pmax[base], pmax[base + 8]);
    g[(size_t)b * 2 * EMBD + EMBD + o] = (psum[base] + psum[base + 8]) * (1.0f / 1024.0f);
}

// ---------------- naive head1: one block per (b,o) ----------------
__global__ __launch_bounds__(256) void head1_naive_kernel(const float* __restrict__ g, const float* __restrict__ l1,
                                                          const float* __restrict__ bnp, float* __restrict__ h1) {
    __shared__ float red[256];
    int tid = threadIdx.x;
    int b = blockIdx.x >> 9, o = blockIdx.x & 511;
    const float* gr = g + (size_t)b * 2 * EMBD;
    const float* lr = l1 + (size_t)o * 2 * EMBD;
    float s = 0.f;
    for (int c = tid; c < 2048; c += 256) s = fmaf(gr[c], lr[c], s);
    red[tid] = s;
    __syncthreads();
    for (int st = 128; st >= 1; st >>= 1) {
        if (tid < st) red[tid] += red[tid + st];
        __syncthreads();
    }
    if (tid == 0) {
        float sc = bnp[o] * rsqrtf(bnp[3 * 512 + o] + EPSF);
        float t0 = (red[0] - bnp[2 * 512 + o]) * sc + bnp[512 + o];
        h1[b * 512 + o] = t0 >= 0.f ? t0 : 0.2f * t0;
    }
}

// ---------------- naive head2: one block per (b,o) ----------------
__global__ __launch_bounds__(256) void head2_naive_kernel(const float* __restrict__ h1, const float* __restrict__ l2w,
                                                          const float* __restrict__ l2b, const float* __restrict__ bnp,
                                                          float* __restrict__ h2) {
    __shared__ float red[256];
    int tid = threadIdx.x;
    int b = blockIdx.x >> 8, o = blockIdx.x & 255;
    const float* hr = h1 + (size_t)b * 512;
    const float* lr = l2w + (size_t)o * 512;
    float s = fmaf(hr[tid], lr[tid], hr[tid + 256] * lr[tid + 256]);
    red[tid] = s;
    __syncthreads();
    for (int st = 128; st >= 1; st >>= 1) {
        if (tid < st) red[tid] += red[tid + st];
        __syncthreads();
    }
    if (tid == 0) {
        float v = red[0] + l2b[o];
        float sc = bnp[o] * rsqrtf(bnp[3 * 256 + o] + EPSF);
        float t0 = (v - bnp[2 * 256 + o]) * sc + bnp[256 + o];
        h2[b * 256 + o] = t0 >= 0.f ? t0 : 0.2f * t0;
    }
}

// ---------------- naive head3: one block per (b,i) -> logits scratch ----------------
__global__ __launch_bounds__(256) void head3_naive_kernel(const float* __restrict__ h2, const float* __restrict__ l3w,
                                                          const float* __restrict__ l3b, float* __restrict__ logits) {
    __shared__ float red[256];
    int tid = threadIdx.x;
    int b = blockIdx.x / 40, i = blockIdx.x % 40;
    red[tid] = h2[(size_t)b * 256 + tid] * l3w[(size_t)i * 256 + tid];
    __syncthreads();
    for (int st = 128; st >= 1; st >>= 1) {
        if (tid < st) red[tid] += red[tid + st];
        __syncthreads();
    }
    if (tid == 0) logits[b * 40 + i] = red[0] + l3b[i];
}

// ---------------- final: out[0..319]=logits (f32), out[320..639]=log_softmax (f32) ----------------
__global__ void final_kernel(const float* __restrict__ logits, float* __restrict__ outp) {
    int b = blockIdx.x;
    if (threadIdx.x != 0) return;
    const float* lr = logits + b * 40;
    float mx = lr[0];
    for (int i = 1; i < 40; ++i) mx = fmaxf(mx, lr[i]);
    float se = 0.f;
    for (int i = 0; i < 40; ++i) se += expf(lr[i] - mx);
    float lse = logf(se);
    for (int i = 0; i < 40; ++i) {
        outp[b * 40 + i]            = lr[i];
        outp[BB * 40 + b * 40 + i]  = lr[i] - mx - lse;
    }
}

extern "C" void kernel_launch(void* const* d_in, const int* in_sizes, int n_in,
                              void* d_out, int out_size, void* d_ws, size_t ws_size,
                              hipStream_t stream) {
    const float* x   = (const float*)d_in[0];
    const float* w1  = (const float*)d_in[1];
    const float* w2  = (const float*)d_in[2];
    const float* w3  = (const float*)d_in[3];
    const float* w4  = (const float*)d_in[4];
    const float* w5  = (const float*)d_in[5];
    const float* l1  = (const float*)d_in[6];
    const float* l2w = (const float*)d_in[7];
    const float* l2b = (const float*)d_in[8];
    const float* l3w = (const float*)d_in[9];
    const float* l3b = (const float*)d_in[10];
    const float* bn1 = (const float*)d_in[11];
    const float* bn2 = (const float*)d_in[12];
    const float* bn3 = (const float*)d_in[13];
    const float* bn4 = (const float*)d_in[14];
    const float* bn5 = (const float*)d_in[15];
    const float* bn6 = (const float*)d_in[16];
    const float* bn7 = (const float*)d_in[17];
    float* outp = (float*)d_out;   // reference outputs are float32

    // workspace carve (floats): xc | ya | yc | gidx | g | h1 | h2 | logits | pmax | psum
    float* xc     = (float*)d_ws;
    float* ya     = xc  + (size_t)BB * 512 * NN;
    float* ycb    = ya  + (size_t)BB * 256 * NN;
    int*  gidx    = (int*)(ycb + (size_t)BB * 256 * NN);
    float* g      = (float*)(gidx + (size_t)BB * NN * KK);
    float* h1     = g  + BB * 2 * EMBD;
    float* h2     = h1 + BB * 512;
    float* logits = h2 + BB * 256;
    float* pmax   = logits + 320;
    float* psum   = pmax + (size_t)BB * 128 * 2 * 8;

    struct Layer { const float* xin; int C; int bstride; const float* w; const float* bn; int O; float* out; };
    Layer L[4] = {
        { x,            3,   3 * NN,   w1, bn1, 64,  xc            },
        { xc,           64,  512 * NN, w2, bn2, 64,  xc + 64 * NN  },
        { xc + 64 * NN, 64,  512 * NN, w3, bn3, 128, xc + 128 * NN },
        { xc + 128 * NN,128, 512 * NN, w4, bn4, 256, xc + 256 * NN },
    };

    size_t lsz = (size_t)(ROWS * NN) * sizeof(float);   // 32 KB
    for (int i = 0; i < 4; ++i) {
        layer_kernel<<<dim3(BB * 128 + BB * (L[i].O / 8)), dim3(256), lsz, stream>>>(
            L[i].xin, L[i].C, L[i].bstride, L[i].w, L[i].O, gidx, ya, ycb);
        gmax2_kernel<<<dim3(BB * (L[i].O / 2) * 4), dim3(256), 0, stream>>>(ya, ycb, gidx, L[i].bn, L[i].O, L[i].out, 512 * NN);
    }
    emb_part_kernel<<<dim3(BB * 256), dim3(128), 0, stream>>>(xc, w5, bn5, pmax, psum);
    emb_comb_kernel<<<dim3(32), dim3(256), 0, stream>>>(pmax, psum, g);
    head1_naive_kernel<<<dim3(BB * 512), dim3(256), 0, stream>>>(g, l1, bn6, h1);
    head2_naive_kernel<<<dim3(BB * 256), dim3(256), 0, stream>>>(h1, l2w, l2b, bn7, h2);
    head3_naive_kernel<<<dim3(BB * 40), dim3(256), 0, stream>>>(h2, l3w, l3b, logits);
    final_kernel<<<dim3(BB), dim3(64), 0, stream>>>(logits, outp);
}